// Round 2
// baseline (13055.975 us; speedup 1.0000x reference)
//
#include <hip/hip_runtime.h>

// ---------------------------------------------------------------------------
// BidirectionalMLP equilibrium relaxation on MI355X.
// s1,s2: [256,4096], s3: [256,10].  25 steps of:
//   s1' = clip(0.5*s1 + CC + 0.25*(r2@bw1))          CC = 0.25*(rx@fw0), const
//   s2' = clip(0.5*s2 + 0.25*(r1@fw1) + 0.25*(r3@bw2))
//   s3' = clip((0.5-beta)*s3 + 0.5*(r2@fw2) + beta*y)
// bf16 MFMA 16x16x32, fp32 accum. Weights transposed once to [N][K] bf16.
// Round 2: software-pipelined K-loop — double-buffered LDS, async
// global_load_lds prefetch 1 iter ahead, raw s_waitcnt vmcnt(N)+s_barrier
// (never vmcnt(0) mid-loop). s3-head FW2T fragments register-prefetched.
// ---------------------------------------------------------------------------

typedef __attribute__((ext_vector_type(4))) float f32x4;
typedef __attribute__((ext_vector_type(8))) short short8;

__device__ __forceinline__ unsigned short f2b(float f) {
    union { float f; unsigned int u; } v;
    v.f = f;
    unsigned int r = v.u + 0x7fffu + ((v.u >> 16) & 1u);
    return (unsigned short)(r >> 16);
}

__device__ __forceinline__ float clamp01(float v) {
    return fminf(fmaxf(v, 0.0f), 1.0f);
}

__device__ __forceinline__ void async16(const unsigned short* g, unsigned short* l) {
    __builtin_amdgcn_global_load_lds(
        (__attribute__((address_space(1))) void*)g,
        (__attribute__((address_space(3))) void*)l,
        16, 0, 0);
}

// barrier helpers: wait only for the OLD iteration's loads, leaving the
// just-issued prefetch in flight.
__device__ __forceinline__ void wb0() { asm volatile("s_waitcnt vmcnt(0)\n\ts_barrier" ::: "memory"); }
__device__ __forceinline__ void wb6() { asm volatile("s_waitcnt vmcnt(6)\n\ts_barrier" ::: "memory"); }
__device__ __forceinline__ void wb8() { asm volatile("s_waitcnt vmcnt(8)\n\ts_barrier" ::: "memory"); }
// read-release barrier: my ds_reads are drained; DMA prefetch stays in flight
__device__ __forceinline__ void rbar() { asm volatile("s_waitcnt lgkmcnt(0)\n\ts_barrier" ::: "memory"); }

// LDS tiles: rows of 8 chunks (16B each); chunk position within a row is
// XOR-swizzled by (row&7) so ds_read_b128 fragment reads spread banks.
__device__ __forceinline__ short8 frag_ld(const unsigned short* lds, int row, int ksel) {
    int chunk = (row << 3) + (ksel ^ (row & 7));
    return *reinterpret_cast<const short8*>(lds + (chunk << 3));
}

__device__ __forceinline__ void stage_tile(
    const unsigned short* __restrict__ Ag, const unsigned short* __restrict__ Bg,
    int K, int M0, int N0, int k0,
    unsigned short* ldsA, unsigned short* ldsB, int tid)
{
#pragma unroll
    for (int r = 0; r < 2; ++r) {  // A: 64 rows x 8 chunks = 512
        int ca = (r << 8) + tid;
        int row = ca >> 3, kcs = ca & 7;
        int kc = kcs ^ (row & 7);
        async16(Ag + (size_t)(M0 + row) * K + k0 + (kc << 3), ldsA + (ca << 3));
    }
#pragma unroll
    for (int r = 0; r < 4; ++r) {  // B: 128 rows x 8 chunks = 1024
        int cb = (r << 8) + tid;
        int row = cb >> 3, kcs = cb & 7;
        int kc = kcs ^ (row & 7);
        async16(Bg + (size_t)(N0 + row) * K + k0 + (kc << 3), ldsB + (cb << 3));
    }
}

// Core: C[64x128] tile of A[256,K] @ B^T[N,K] at (M0,N0). 256 threads, 4 waves
// of 32x64. BK=64, double-buffered, 1-deep async prefetch. doS3 is
// BLOCK-uniform (scalar branch -> exact vmcnt accounting per wave); when set,
// all waves also accumulate acc2 = A_tile @ FW2T^T (16 cols), FW2T fragments
// register-prefetched one iteration ahead.
__device__ __forceinline__ void gemm_core(
    const unsigned short* __restrict__ Ag,
    const unsigned short* __restrict__ Bg,
    int K, int M0, int N0,
    f32x4* acc,
    const unsigned short* __restrict__ FW2T, f32x4* acc2, bool doS3,
    int tid)
{
    __shared__ __align__(16) unsigned short ldsA[2][64 * 64];
    __shared__ __align__(16) unsigned short ldsB[2][128 * 64];

    const int lane = tid & 63;
    const int wave = tid >> 6;
    const int wm = (wave >> 1) << 5;   // 0 / 32
    const int wn = (wave & 1) << 6;    // 0 / 64
    const int fr = lane & 15;
    const int fq = lane >> 4;
    const int nks = K >> 6;

    short8 bs[2][2];

    // prologue: stage tile 0, prefetch FW2T fragments for tile 0
    stage_tile(Ag, Bg, K, M0, N0, 0, ldsA[0], ldsB[0], tid);
    if (doS3) {
        const unsigned short* p = FW2T + (size_t)fr * 4096 + (fq << 3);
        bs[0][0] = *reinterpret_cast<const short8*>(p);
        bs[0][1] = *reinterpret_cast<const short8*>(p + 32);
    }

    for (int ks = 0; ks < nks; ++ks) {
        const int cur = ks & 1, nxt = cur ^ 1;
        const int k0 = ks << 6;
        const bool more = (ks + 1 < nks);

        if (doS3) {
            if (more) {
                const unsigned short* p = FW2T + (size_t)fr * 4096 + k0 + 64 + (fq << 3);
                bs[nxt][0] = *reinterpret_cast<const short8*>(p);
                bs[nxt][1] = *reinterpret_cast<const short8*>(p + 32);
                stage_tile(Ag, Bg, K, M0, N0, k0 + 64, ldsA[nxt], ldsB[nxt], tid);
                wb8();   // drain prev iter's 6 stage + 2 bs; leave new 8 in flight
            } else {
                wb0();
            }
        } else {
            if (more) {
                stage_tile(Ag, Bg, K, M0, N0, k0 + 64, ldsA[nxt], ldsB[nxt], tid);
                wb6();   // drain prev iter's 6 stage; leave new 6 in flight
            } else {
                wb0();
            }
        }

        const unsigned short* lA = ldsA[cur];
        const unsigned short* lB = ldsB[cur];
#pragma unroll
        for (int ki = 0; ki < 2; ++ki) {
            const int ksel = (ki << 2) + fq;
            short8 a0 = frag_ld(lA, wm + fr, ksel);
            short8 a1 = frag_ld(lA, wm + 16 + fr, ksel);
            short8 b0 = frag_ld(lB, wn + fr, ksel);
            short8 b1 = frag_ld(lB, wn + 16 + fr, ksel);
            short8 b2 = frag_ld(lB, wn + 32 + fr, ksel);
            short8 b3 = frag_ld(lB, wn + 48 + fr, ksel);
            acc[0] = __builtin_amdgcn_mfma_f32_16x16x32_bf16(a0, b0, acc[0], 0, 0, 0);
            acc[1] = __builtin_amdgcn_mfma_f32_16x16x32_bf16(a0, b1, acc[1], 0, 0, 0);
            acc[2] = __builtin_amdgcn_mfma_f32_16x16x32_bf16(a0, b2, acc[2], 0, 0, 0);
            acc[3] = __builtin_amdgcn_mfma_f32_16x16x32_bf16(a0, b3, acc[3], 0, 0, 0);
            acc[4] = __builtin_amdgcn_mfma_f32_16x16x32_bf16(a1, b0, acc[4], 0, 0, 0);
            acc[5] = __builtin_amdgcn_mfma_f32_16x16x32_bf16(a1, b1, acc[5], 0, 0, 0);
            acc[6] = __builtin_amdgcn_mfma_f32_16x16x32_bf16(a1, b2, acc[6], 0, 0, 0);
            acc[7] = __builtin_amdgcn_mfma_f32_16x16x32_bf16(a1, b3, acc[7], 0, 0, 0);
            if (doS3) {
                acc2[0] = __builtin_amdgcn_mfma_f32_16x16x32_bf16(a0, bs[cur][ki], acc2[0], 0, 0, 0);
                acc2[1] = __builtin_amdgcn_mfma_f32_16x16x32_bf16(a1, bs[cur][ki], acc2[1], 0, 0, 0);
            }
        }
        rbar();   // all waves done reading buf[cur] before it is restaged
    }
}

// One relaxation step. Grid = 256 blocks: [0,128) GEMM1 (-> s1, s3),
// [128,256) GEMM2 (-> s2). 64x128 tiles over [256, 4096].
__global__ __launch_bounds__(256) void step_kernel(
    const unsigned short* __restrict__ R2old,
    const unsigned short* __restrict__ R1old,
    const float* __restrict__ S1old, const float* __restrict__ S2old,
    const float* __restrict__ S3old,
    float* __restrict__ S1new, float* __restrict__ S2new, float* __restrict__ S3new,
    unsigned short* __restrict__ R1new, unsigned short* __restrict__ R2new,
    const unsigned short* __restrict__ B1T, const unsigned short* __restrict__ B2T,
    const unsigned short* __restrict__ FW2T,
    const float* __restrict__ CC, const float* __restrict__ bw2,
    const float* __restrict__ y, float beta)
{
    const int tid = threadIdx.x;
    const int b = blockIdx.x;
    const bool g1 = (b < 128);
    int mt, nt;
    const unsigned short *A, *B;
    if (g1) { mt = b >> 5; nt = b & 31; A = R2old; B = B1T; }
    else    { int bb = b - 128; mt = bb >> 5; nt = bb & 31; A = R1old; B = B2T; }
    const int M0 = mt << 6, N0 = nt << 7;

    const int lane = tid & 63;
    const int wave = tid >> 6;
    const int wm = (wave >> 1) << 5;
    const int wn = (wave & 1) << 6;
    const int fr = lane & 15;
    const int fq = lane >> 4;
    // s3 head: BLOCK-uniform predicate (exact vmcnt accounting); all 4 waves
    // run the acc2 MFMAs, only wn==0 waves write s3.
    const bool doS3 = g1 && (nt == 0);

    f32x4 acc[8], acc2[2];
    f32x4 zero = {0.f, 0.f, 0.f, 0.f};
#pragma unroll
    for (int i = 0; i < 8; ++i) acc[i] = zero;
    acc2[0] = zero; acc2[1] = zero;

    gemm_core(A, B, 4096, M0, N0, acc, FW2T, acc2, doS3, tid);

    if (g1) {
#pragma unroll
        for (int i = 0; i < 8; ++i) {
            int im = i >> 2, in_ = i & 3;
            int n = N0 + wn + (in_ << 4) + fr;
#pragma unroll
            for (int rr = 0; rr < 4; ++rr) {
                int m = M0 + wm + (im << 4) + (fq << 2) + rr;
                size_t o = (size_t)m * 4096 + n;
                float v = 0.5f * S1old[o] + CC[o] + 0.25f * acc[i][rr];
                v = clamp01(v);
                S1new[o] = v;
                R1new[o] = f2b(v);
            }
        }
        if (doS3 && wn == 0 && fr < 10) {
#pragma unroll
            for (int im = 0; im < 2; ++im) {
#pragma unroll
                for (int rr = 0; rr < 4; ++rr) {
                    int m = M0 + wm + (im << 4) + (fq << 2) + rr;
                    float s3 = S3old[m * 10 + fr];
                    float v = (0.5f - beta) * s3 + 0.5f * acc2[im][rr]
                              + beta * y[m * 10 + fr];
                    v = clamp01(v);
                    S3new[m * 10 + fr] = v;
                }
            }
        }
    } else {
#pragma unroll
        for (int i = 0; i < 8; ++i) {
            int im = i >> 2, in_ = i & 3;
            int n = N0 + wn + (in_ << 4) + fr;
#pragma unroll
            for (int rr = 0; rr < 4; ++rr) {
                int m = M0 + wm + (im << 4) + (fq << 2) + rr;
                size_t o = (size_t)m * 4096 + n;
                float dot = 0.f;
#pragma unroll
                for (int j = 0; j < 10; ++j)
                    dot += S3old[m * 10 + j] * bw2[j * 4096 + n];
                float v = 0.5f * S2old[o] + 0.25f * acc[i][rr] + 0.25f * dot;
                v = clamp01(v);
                S2new[o] = v;
                R2new[o] = f2b(v);
            }
        }
    }
}

// CC = 0.25*(rx @ fw0). A = RX [256,1024] bf16, B = FW0T [4096,1024] bf16.
__global__ __launch_bounds__(256) void c1_kernel(
    const unsigned short* __restrict__ RX,
    const unsigned short* __restrict__ FW0T,
    float* __restrict__ CC)
{
    const int tid = threadIdx.x;
    const int b = blockIdx.x;
    const int mt = b >> 5, nt = b & 31;
    const int M0 = mt << 6, N0 = nt << 7;

    f32x4 acc[8], acc2[2];
    f32x4 zero = {0.f, 0.f, 0.f, 0.f};
#pragma unroll
    for (int i = 0; i < 8; ++i) acc[i] = zero;
    acc2[0] = zero; acc2[1] = zero;

    gemm_core(RX, FW0T, 1024, M0, N0, acc, nullptr, acc2, false, tid);

    const int lane = tid & 63;
    const int wave = tid >> 6;
    const int wm = (wave >> 1) << 5;
    const int wn = (wave & 1) << 6;
    const int fr = lane & 15;
    const int fq = lane >> 4;
#pragma unroll
    for (int i = 0; i < 8; ++i) {
        int im = i >> 2, in_ = i & 3;
        int n = N0 + wn + (in_ << 4) + fr;
#pragma unroll
        for (int rr = 0; rr < 4; ++rr) {
            int m = M0 + wm + (im << 4) + (fq << 2) + rr;
            CC[(size_t)m * 4096 + n] = 0.25f * acc[i][rr];
        }
    }
}

// src [R][C] fp32 row-major -> dst [C][R] bf16 (dst row stride = R).
__global__ __launch_bounds__(256) void transpose_cvt(
    const float* __restrict__ src, unsigned short* __restrict__ dst,
    int R, int C)
{
    __shared__ float t[32][33];
    const int c0 = blockIdx.x << 5, r0 = blockIdx.y << 5;
    const int tx = threadIdx.x & 31, ty = threadIdx.x >> 5;   // ty: 0..7
#pragma unroll
    for (int i = 0; i < 32; i += 8)
        t[ty + i][tx] = src[(size_t)(r0 + ty + i) * C + (c0 + tx)];
    __syncthreads();
#pragma unroll
    for (int i = 0; i < 32; i += 8)
        dst[(size_t)(c0 + ty + i) * R + (r0 + tx)] = f2b(t[tx][ty + i]);
}

// FW2T fill, rx convert, zero-init of ping buffers.
__global__ __launch_bounds__(256) void misc_init(
    const float* __restrict__ x, const float* __restrict__ fw2,
    unsigned short* __restrict__ FW2T, unsigned short* __restrict__ RX,
    float* __restrict__ S1, float* __restrict__ S2, float* __restrict__ S3,
    unsigned short* __restrict__ R1, unsigned short* __restrict__ R2)
{
    const int stride = gridDim.x * blockDim.x;
    const int t0 = blockIdx.x * blockDim.x + threadIdx.x;
    for (int i = t0; i < 16 * 4096; i += stride) {      // FW2T[n][k] = fw2[k][n]
        int n = i >> 12, k = i & 4095;
        FW2T[i] = (n < 10) ? f2b(fw2[k * 10 + n]) : (unsigned short)0;
    }
    for (int i = t0; i < 256 * 1024; i += stride)
        RX[i] = f2b(clamp01(x[i]));
    for (int i = t0; i < 256 * 4096; i += stride) {
        S1[i] = 0.f; S2[i] = 0.f; R1[i] = 0; R2[i] = 0;
    }
    for (int i = t0; i < 2560; i += stride) S3[i] = 0.f;
}

__global__ __launch_bounds__(256) void pack_kernel(
    const float* __restrict__ S1, const float* __restrict__ S2,
    const float* __restrict__ S3, float* __restrict__ out)
{
    const int stride = gridDim.x * blockDim.x;
    for (int i = blockIdx.x * blockDim.x + threadIdx.x; i < 256 * 8202; i += stride) {
        int m = i / 8202, c = i - m * 8202;
        float v;
        if (c < 4096)       v = S1[(size_t)m * 4096 + c];
        else if (c < 8192)  v = S2[(size_t)m * 4096 + (c - 4096)];
        else                v = S3[m * 10 + (c - 8192)];
        out[i] = v;
    }
}

extern "C" void kernel_launch(void* const* d_in, const int* in_sizes, int n_in,
                              void* d_out, int out_size, void* d_ws, size_t ws_size,
                              hipStream_t stream) {
    const float* x   = (const float*)d_in[0];
    const float* fw0 = (const float*)d_in[1];
    const float* fw1 = (const float*)d_in[2];
    const float* fw2 = (const float*)d_in[3];
    // d_in[4] = bw0 : unused by the reference
    const float* bw1 = (const float*)d_in[5];
    const float* bw2 = (const float*)d_in[6];
    const float* y   = (const float*)d_in[7];

    char* ws = (char*)d_ws;
    // workspace layout (bytes)
    unsigned short* B1T  = (unsigned short*)(ws + 0);          // 4096x4096 bf16
    unsigned short* B2T  = (unsigned short*)(ws + 33554432);   // 4096x4096 bf16
    unsigned short* FW0T = (unsigned short*)(ws + 67108864);   // 4096x1024 bf16
    unsigned short* FW2T = (unsigned short*)(ws + 75497472);   // 16x4096 bf16
    unsigned short* RX   = (unsigned short*)(ws + 75628544);   // 256x1024 bf16
    float*          CC   = (float*)(ws + 76152832);            // 256x4096 f32
    float*          S1f  = (float*)(ws + 80347136);            // 2 x 256x4096 f32
    float*          S2f  = (float*)(ws + 88735744);            // 2 x 256x4096 f32
    float*          S3f  = (float*)(ws + 97124352);            // 2 x 256x10 f32
    unsigned short* R1   = (unsigned short*)(ws + 97144832);   // 2 x 256x4096 bf16
    unsigned short* R2   = (unsigned short*)(ws + 101339136);  // 2 x 256x4096 bf16
    // total ~105.6 MB

    const size_t SB = 256 * 4096;  // state buffer elems
    dim3 blk(256);

    transpose_cvt<<<dim3(128, 128), blk, 0, stream>>>(bw1, B1T, 4096, 4096);
    transpose_cvt<<<dim3(128, 128), blk, 0, stream>>>(fw1, B2T, 4096, 4096);
    transpose_cvt<<<dim3(128, 32),  blk, 0, stream>>>(fw0, FW0T, 1024, 4096);
    misc_init<<<512, blk, 0, stream>>>(x, fw2, FW2T, RX,
                                       S1f, S2f, S3f, R1, R2);
    c1_kernel<<<128, blk, 0, stream>>>(RX, FW0T, CC);

    for (int t = 0; t < 25; ++t) {
        const int o = t & 1, nw = o ^ 1;
        const float beta = (t < 20) ? 0.0f : 0.5f;
        step_kernel<<<256, blk, 0, stream>>>(
            R2 + o * SB, R1 + o * SB,
            S1f + o * SB, S2f + o * SB, S3f + o * 2560,
            S1f + nw * SB, S2f + nw * SB, S3f + nw * 2560,
            R1 + nw * SB, R2 + nw * SB,
            B1T, B2T, FW2T, CC, bw2, y, beta);
    }

    pack_kernel<<<2048, blk, 0, stream>>>(S1f + SB, S2f + SB, S3f + 2560,
                                          (float*)d_out);
}

// Round 3
// 2186.820 us; speedup vs baseline: 5.9703x; 5.9703x over previous
//
#include <hip/hip_runtime.h>

// ---------------------------------------------------------------------------
// BidirectionalMLP equilibrium relaxation on MI355X.
// s1,s2: [256,4096], s3: [256,10].  25 steps of:
//   s1' = clip(0.5*s1 + CC + 0.25*(r2@bw1))          CC = 0.25*(rx@fw0), const
//   s2' = clip(0.5*s2 + 0.25*(r1@fw1) + 0.25*(r3@bw2))
//   s3' = clip((0.5-beta)*s3 + 0.5*(r2@fw2) + beta*y)
// bf16 MFMA 16x16x32, fp32 accum. Weights transposed once to [N][K] bf16.
// Round 3: revert to round-1 two-barrier staging (raw-asm pipeline regressed
// 6x — compiler serialized the DMA stream). Single change: 64x64 tiles ->
// 512 blocks = 2 blocks/CU so two independent barrier domains interleave and
// mask the vmcnt(0) drain latency (round-1 was 1 block/CU, 27% memory duty).
// ---------------------------------------------------------------------------

typedef __attribute__((ext_vector_type(4))) float f32x4;
typedef __attribute__((ext_vector_type(8))) short short8;

__device__ __forceinline__ unsigned short f2b(float f) {
    union { float f; unsigned int u; } v;
    v.f = f;
    unsigned int r = v.u + 0x7fffu + ((v.u >> 16) & 1u);
    return (unsigned short)(r >> 16);
}

__device__ __forceinline__ float clamp01(float v) {
    return fminf(fmaxf(v, 0.0f), 1.0f);
}

__device__ __forceinline__ void async16(const unsigned short* g, unsigned short* l) {
    __builtin_amdgcn_global_load_lds(
        (__attribute__((address_space(1))) void*)g,
        (__attribute__((address_space(3))) void*)l,
        16, 0, 0);
}

// LDS tiles: rows of 8 chunks (16B each); chunk position within a row is
// XOR-swizzled by (row&7) so ds_read_b128 fragment reads spread banks.
__device__ __forceinline__ short8 frag_ld(const unsigned short* lds, int row, int ksel) {
    int chunk = (row << 3) + (ksel ^ (row & 7));
    return *reinterpret_cast<const short8*>(lds + (chunk << 3));
}

// Core: C[64x64] tile of A[256,K] @ B^T[N,K] at (M0,N0). 256 threads, 4 waves
// in 2x2 layout (each wave 32x32). BK=64, single-buffered, round-1 structure.
// doS3 wave-uniform: wn==0 waves of the nt==0 GEMM1 blocks also accumulate
// acc2 = A_rows @ FW2T^T (16 cols) reusing A fragments.
__device__ __forceinline__ void gemm_core(
    const unsigned short* __restrict__ Ag,
    const unsigned short* __restrict__ Bg,
    int K, int M0, int N0,
    unsigned short* ldsA, unsigned short* ldsB,
    f32x4* acc,
    const unsigned short* __restrict__ FW2T, f32x4* acc2, bool doS3,
    int tid)
{
    const int lane = tid & 63;
    const int wave = tid >> 6;
    const int wm = (wave >> 1) << 5;   // 0 / 32
    const int wn = (wave & 1) << 5;    // 0 / 32
    const int fr = lane & 15;
    const int fq = lane >> 4;
    const int nks = K >> 6;

    for (int ks = 0; ks < nks; ++ks) {
        const int k0 = ks << 6;
        __syncthreads();               // previous compute done before restage
#pragma unroll
        for (int r = 0; r < 2; ++r) {  // A: 64 rows x 8 chunks = 512
            int ca = (r << 8) + tid;
            int row = ca >> 3, kcs = ca & 7;
            int kc = kcs ^ (row & 7);
            async16(Ag + (size_t)(M0 + row) * K + k0 + (kc << 3), ldsA + (ca << 3));
        }
#pragma unroll
        for (int r = 0; r < 2; ++r) {  // B: 64 rows x 8 chunks = 512
            int cb = (r << 8) + tid;
            int row = cb >> 3, kcs = cb & 7;
            int kc = kcs ^ (row & 7);
            async16(Bg + (size_t)(N0 + row) * K + k0 + (kc << 3), ldsB + (cb << 3));
        }
        __syncthreads();               // drains vmcnt -> LDS valid
#pragma unroll
        for (int ki = 0; ki < 2; ++ki) {
            const int ksel = (ki << 2) + fq;
            short8 a0 = frag_ld(ldsA, wm + fr, ksel);
            short8 a1 = frag_ld(ldsA, wm + 16 + fr, ksel);
            short8 b0 = frag_ld(ldsB, wn + fr, ksel);
            short8 b1 = frag_ld(ldsB, wn + 16 + fr, ksel);
            acc[0] = __builtin_amdgcn_mfma_f32_16x16x32_bf16(a0, b0, acc[0], 0, 0, 0);
            acc[1] = __builtin_amdgcn_mfma_f32_16x16x32_bf16(a0, b1, acc[1], 0, 0, 0);
            acc[2] = __builtin_amdgcn_mfma_f32_16x16x32_bf16(a1, b0, acc[2], 0, 0, 0);
            acc[3] = __builtin_amdgcn_mfma_f32_16x16x32_bf16(a1, b1, acc[3], 0, 0, 0);
            if (doS3) {
                short8 bs = *reinterpret_cast<const short8*>(
                    FW2T + (size_t)fr * 4096 + k0 + (ksel << 3));
                acc2[0] = __builtin_amdgcn_mfma_f32_16x16x32_bf16(a0, bs, acc2[0], 0, 0, 0);
                acc2[1] = __builtin_amdgcn_mfma_f32_16x16x32_bf16(a1, bs, acc2[1], 0, 0, 0);
            }
        }
    }
}

// One relaxation step. Grid = 512 blocks: [0,256) GEMM1 (-> s1, s3),
// [256,512) GEMM2 (-> s2). 64x64 tiles over [256, 4096]. nt is the fast
// block index so panel-mates (b, b+64, ...) land on the same XCD (64%8==0).
__global__ __launch_bounds__(256) void step_kernel(
    const unsigned short* __restrict__ R2old,
    const unsigned short* __restrict__ R1old,
    const float* __restrict__ S1old, const float* __restrict__ S2old,
    const float* __restrict__ S3old,
    float* __restrict__ S1new, float* __restrict__ S2new, float* __restrict__ S3new,
    unsigned short* __restrict__ R1new, unsigned short* __restrict__ R2new,
    const unsigned short* __restrict__ B1T, const unsigned short* __restrict__ B2T,
    const unsigned short* __restrict__ FW2T,
    const float* __restrict__ CC, const float* __restrict__ bw2,
    const float* __restrict__ y, float beta)
{
    __shared__ __align__(16) unsigned short ldsA[64 * 64];
    __shared__ __align__(16) unsigned short ldsB[64 * 64];
    const int tid = threadIdx.x;
    const int b = blockIdx.x;
    const bool g1 = (b < 256);
    int mt, nt;
    const unsigned short *A, *B;
    if (g1) { mt = b >> 6; nt = b & 63; A = R2old; B = B1T; }
    else    { int bb = b - 256; mt = bb >> 6; nt = bb & 63; A = R1old; B = B2T; }
    const int M0 = mt << 6, N0 = nt << 6;

    const int lane = tid & 63;
    const int wave = tid >> 6;
    const int wm = (wave >> 1) << 5;
    const int wn = (wave & 1) << 5;
    const int fr = lane & 15;
    const int fq = lane >> 4;
    // s3 head: wave-uniform predicate; wn==0 waves of nt==0 GEMM1 blocks
    const bool doS3 = g1 && (nt == 0) && (wn == 0);

    f32x4 acc[4], acc2[2];
    f32x4 zero = {0.f, 0.f, 0.f, 0.f};
#pragma unroll
    for (int i = 0; i < 4; ++i) acc[i] = zero;
    acc2[0] = zero; acc2[1] = zero;

    gemm_core(A, B, 4096, M0, N0, ldsA, ldsB, acc, FW2T, acc2, doS3, tid);

    if (g1) {
#pragma unroll
        for (int i = 0; i < 4; ++i) {
            int im = i >> 1, in_ = i & 1;
            int n = N0 + wn + (in_ << 4) + fr;
#pragma unroll
            for (int rr = 0; rr < 4; ++rr) {
                int m = M0 + wm + (im << 4) + (fq << 2) + rr;
                size_t o = (size_t)m * 4096 + n;
                float v = 0.5f * S1old[o] + CC[o] + 0.25f * acc[i][rr];
                v = clamp01(v);
                S1new[o] = v;
                R1new[o] = f2b(v);
            }
        }
        if (doS3 && fr < 10) {
#pragma unroll
            for (int im = 0; im < 2; ++im) {
#pragma unroll
                for (int rr = 0; rr < 4; ++rr) {
                    int m = M0 + wm + (im << 4) + (fq << 2) + rr;
                    float s3 = S3old[m * 10 + fr];
                    float v = (0.5f - beta) * s3 + 0.5f * acc2[im][rr]
                              + beta * y[m * 10 + fr];
                    v = clamp01(v);
                    S3new[m * 10 + fr] = v;
                }
            }
        }
    } else {
#pragma unroll
        for (int i = 0; i < 4; ++i) {
            int im = i >> 1, in_ = i & 1;
            int n = N0 + wn + (in_ << 4) + fr;
#pragma unroll
            for (int rr = 0; rr < 4; ++rr) {
                int m = M0 + wm + (im << 4) + (fq << 2) + rr;
                size_t o = (size_t)m * 4096 + n;
                float dot = 0.f;
#pragma unroll
                for (int j = 0; j < 10; ++j)
                    dot += S3old[m * 10 + j] * bw2[j * 4096 + n];
                float v = 0.5f * S2old[o] + 0.25f * acc[i][rr] + 0.25f * dot;
                v = clamp01(v);
                S2new[o] = v;
                R2new[o] = f2b(v);
            }
        }
    }
}

// CC = 0.25*(rx @ fw0). A = RX [256,1024] bf16, B = FW0T [4096,1024] bf16.
// 64x64 tiles -> 256 blocks.
__global__ __launch_bounds__(256) void c1_kernel(
    const unsigned short* __restrict__ RX,
    const unsigned short* __restrict__ FW0T,
    float* __restrict__ CC)
{
    __shared__ __align__(16) unsigned short ldsA[64 * 64];
    __shared__ __align__(16) unsigned short ldsB[64 * 64];
    const int tid = threadIdx.x;
    const int b = blockIdx.x;
    const int mt = b >> 6, nt = b & 63;
    const int M0 = mt << 6, N0 = nt << 6;

    f32x4 acc[4], acc2[2];
    f32x4 zero = {0.f, 0.f, 0.f, 0.f};
#pragma unroll
    for (int i = 0; i < 4; ++i) acc[i] = zero;
    acc2[0] = zero; acc2[1] = zero;

    gemm_core(RX, FW0T, 1024, M0, N0, ldsA, ldsB, acc, nullptr, acc2, false, tid);

    const int lane = tid & 63;
    const int wave = tid >> 6;
    const int wm = (wave >> 1) << 5;
    const int wn = (wave & 1) << 5;
    const int fr = lane & 15;
    const int fq = lane >> 4;
#pragma unroll
    for (int i = 0; i < 4; ++i) {
        int im = i >> 1, in_ = i & 1;
        int n = N0 + wn + (in_ << 4) + fr;
#pragma unroll
        for (int rr = 0; rr < 4; ++rr) {
            int m = M0 + wm + (im << 4) + (fq << 2) + rr;
            CC[(size_t)m * 4096 + n] = 0.25f * acc[i][rr];
        }
    }
}

// src [R][C] fp32 row-major -> dst [C][R] bf16 (dst row stride = R).
__global__ __launch_bounds__(256) void transpose_cvt(
    const float* __restrict__ src, unsigned short* __restrict__ dst,
    int R, int C)
{
    __shared__ float t[32][33];
    const int c0 = blockIdx.x << 5, r0 = blockIdx.y << 5;
    const int tx = threadIdx.x & 31, ty = threadIdx.x >> 5;   // ty: 0..7
#pragma unroll
    for (int i = 0; i < 32; i += 8)
        t[ty + i][tx] = src[(size_t)(r0 + ty + i) * C + (c0 + tx)];
    __syncthreads();
#pragma unroll
    for (int i = 0; i < 32; i += 8)
        dst[(size_t)(c0 + ty + i) * R + (r0 + tx)] = f2b(t[tx][ty + i]);
}

// FW2T fill, rx convert, zero-init of ping buffers.
__global__ __launch_bounds__(256) void misc_init(
    const float* __restrict__ x, const float* __restrict__ fw2,
    unsigned short* __restrict__ FW2T, unsigned short* __restrict__ RX,
    float* __restrict__ S1, float* __restrict__ S2, float* __restrict__ S3,
    unsigned short* __restrict__ R1, unsigned short* __restrict__ R2)
{
    const int stride = gridDim.x * blockDim.x;
    const int t0 = blockIdx.x * blockDim.x + threadIdx.x;
    for (int i = t0; i < 16 * 4096; i += stride) {      // FW2T[n][k] = fw2[k][n]
        int n = i >> 12, k = i & 4095;
        FW2T[i] = (n < 10) ? f2b(fw2[k * 10 + n]) : (unsigned short)0;
    }
    for (int i = t0; i < 256 * 1024; i += stride)
        RX[i] = f2b(clamp01(x[i]));
    for (int i = t0; i < 256 * 4096; i += stride) {
        S1[i] = 0.f; S2[i] = 0.f; R1[i] = 0; R2[i] = 0;
    }
    for (int i = t0; i < 2560; i += stride) S3[i] = 0.f;
}

__global__ __launch_bounds__(256) void pack_kernel(
    const float* __restrict__ S1, const float* __restrict__ S2,
    const float* __restrict__ S3, float* __restrict__ out)
{
    const int stride = gridDim.x * blockDim.x;
    for (int i = blockIdx.x * blockDim.x + threadIdx.x; i < 256 * 8202; i += stride) {
        int m = i / 8202, c = i - m * 8202;
        float v;
        if (c < 4096)       v = S1[(size_t)m * 4096 + c];
        else if (c < 8192)  v = S2[(size_t)m * 4096 + (c - 4096)];
        else                v = S3[m * 10 + (c - 8192)];
        out[i] = v;
    }
}

extern "C" void kernel_launch(void* const* d_in, const int* in_sizes, int n_in,
                              void* d_out, int out_size, void* d_ws, size_t ws_size,
                              hipStream_t stream) {
    const float* x   = (const float*)d_in[0];
    const float* fw0 = (const float*)d_in[1];
    const float* fw1 = (const float*)d_in[2];
    const float* fw2 = (const float*)d_in[3];
    // d_in[4] = bw0 : unused by the reference
    const float* bw1 = (const float*)d_in[5];
    const float* bw2 = (const float*)d_in[6];
    const float* y   = (const float*)d_in[7];

    char* ws = (char*)d_ws;
    // workspace layout (bytes)
    unsigned short* B1T  = (unsigned short*)(ws + 0);          // 4096x4096 bf16
    unsigned short* B2T  = (unsigned short*)(ws + 33554432);   // 4096x4096 bf16
    unsigned short* FW0T = (unsigned short*)(ws + 67108864);   // 4096x1024 bf16
    unsigned short* FW2T = (unsigned short*)(ws + 75497472);   // 16x4096 bf16
    unsigned short* RX   = (unsigned short*)(ws + 75628544);   // 256x1024 bf16
    float*          CC   = (float*)(ws + 76152832);            // 256x4096 f32
    float*          S1f  = (float*)(ws + 80347136);            // 2 x 256x4096 f32
    float*          S2f  = (float*)(ws + 88735744);            // 2 x 256x4096 f32
    float*          S3f  = (float*)(ws + 97124352);            // 2 x 256x10 f32
    unsigned short* R1   = (unsigned short*)(ws + 97144832);   // 2 x 256x4096 bf16
    unsigned short* R2   = (unsigned short*)(ws + 101339136);  // 2 x 256x4096 bf16
    // total ~105.6 MB

    const size_t SB = 256 * 4096;  // state buffer elems
    dim3 blk(256);

    transpose_cvt<<<dim3(128, 128), blk, 0, stream>>>(bw1, B1T, 4096, 4096);
    transpose_cvt<<<dim3(128, 128), blk, 0, stream>>>(fw1, B2T, 4096, 4096);
    transpose_cvt<<<dim3(128, 32),  blk, 0, stream>>>(fw0, FW0T, 1024, 4096);
    misc_init<<<512, blk, 0, stream>>>(x, fw2, FW2T, RX,
                                       S1f, S2f, S3f, R1, R2);
    c1_kernel<<<256, blk, 0, stream>>>(RX, FW0T, CC);

    for (int t = 0; t < 25; ++t) {
        const int o = t & 1, nw = o ^ 1;
        const float beta = (t < 20) ? 0.0f : 0.5f;
        step_kernel<<<512, blk, 0, stream>>>(
            R2 + o * SB, R1 + o * SB,
            S1f + o * SB, S2f + o * SB, S3f + o * 2560,
            S1f + nw * SB, S2f + nw * SB, S3f + nw * 2560,
            R1 + nw * SB, R2 + nw * SB,
            B1T, B2T, FW2T, CC, bw2, y, beta);
    }

    pack_kernel<<<2048, blk, 0, stream>>>(S1f + SB, S2f + SB, S3f + 2560,
                                          (float*)d_out);
}